// Round 9
// baseline (89.786 us; speedup 1.0000x reference)
//
#include <hip/hip_runtime.h>

// 5x5 median, zero pad. Packed-f16: each lane computes 2 horizontally adjacent
// outputs via v_pk_min_f16 / v_pk_max_f16. Strip height V=8.
// R8: branchless edge handling — loads are unconditional at clamped in-bounds
// addresses (clamp hoisted out of the loop); zero-padding applied via bitwise
// AND masks on the packed f16 values (+0.0 fill, exact). Removes the per-PROC
// divergent exec-mask branches the okL?/okR? ternaries forced (compiler can't
// speculate possibly-faulting loads).
// Correctness: fp16 conversion is monotone -> median(cvt(x)) == cvt(median(x));
// only error is fp16 rounding of the final median (measured absmax 7.8e-3,
// threshold 2.8e-2). Input is randn -> no NaN/inf concerns.

typedef __fp16 h2 __attribute__((ext_vector_type(2)));

#define MIN2(a, b) __builtin_elementwise_min((a), (b))
#define MAX2(a, b) __builtin_elementwise_max((a), (b))

__device__ __forceinline__ void cswap(h2& a, h2& b) {
    h2 lo = MIN2(a, b);
    h2 hi = MAX2(a, b);
    a = lo; b = hi;
}

__device__ __forceinline__ h2 andmask(h2 v, unsigned m) {
    unsigned u;
    __builtin_memcpy(&u, &v, 4);
    u &= m;
    h2 r;
    __builtin_memcpy(&r, &u, 4);
    return r;
}

#define SORT4 { cswap(v0,v1); cswap(v2,v3); cswap(v0,v2); cswap(v1,v3); cswap(v1,v2); }

// top-2 (sorted) of 5
#define COL_TOP2(x0,x1,x2,x3,x4,o3,o4) { \
    h2 lo01=MIN2(x0,x1), hi01=MAX2(x0,x1); \
    h2 lo23=MIN2(x2,x3), hi23=MAX2(x2,x3); \
    h2 mx4 = MAX2(hi01,hi23); \
    h2 s4  = MAX2(MIN2(hi01,hi23), MAX2(lo01,lo23)); \
    h2 hi  = MAX2(mx4, x4), lo = MIN2(mx4, x4); \
    (o4) = hi; (o3) = MAX2(s4, lo); }

// bottom-2 (sorted) of 5
#define COL_BOT2(x0,x1,x2,x3,x4,o0,o1) { \
    h2 lo01=MIN2(x0,x1), hi01=MAX2(x0,x1); \
    h2 lo23=MIN2(x2,x3), hi23=MAX2(x2,x3); \
    h2 mn4 = MIN2(lo01,lo23); \
    h2 s4  = MIN2(MAX2(lo01,lo23), MIN2(hi01,hi23)); \
    h2 lo  = MIN2(mn4, x4), hi = MAX2(mn4, x4); \
    (o0) = lo; (o1) = MIN2(s4, hi); }

#define COL_TOP3(a0,a1,a2,a3,a4,o2,o3,o4) { \
    h2 v0=a0,v1=a1,v2=a2,v3=a3,v4=a4; SORT4; \
    cswap(v3,v4); cswap(v2,v3); cswap(v1,v2); (o2)=v2; (o3)=v3; (o4)=v4; (void)v0; }

#define COL_MID3(a0,a1,a2,a3,a4,o1,o2,o3) { \
    h2 v0=a0,v1=a1,v2=a2,v3=a3,v4=a4; SORT4; \
    cswap(v3,v4); cswap(v2,v3); cswap(v1,v2); cswap(v0,v1); (o1)=v1; (o2)=v2; (o3)=v3; }

#define COL_BOT3(a0,a1,a2,a3,a4,o0,o1,o2) { \
    h2 v0=a0,v1=a1,v2=a2,v3=a3,v4=a4; SORT4; \
    cswap(v0,v4); cswap(v1,v4); cswap(v2,v4); (o0)=v0; (o1)=v1; (o2)=v2; (void)v3; }

// odd-even merge(2,3): sorted (a0<=a1) + (p0<=p1<=p2) -> sorted L0..L4
#define MERGE23(a0,a1,p0,p1,p2,L0,L1,L2,L3,L4) { \
    h2 e0 = MIN2(a0,p0), t = MAX2(a0,p0); \
    h2 e1 = MIN2(t,p2),  e2 = MAX2(t,p2); \
    h2 o0 = MIN2(a1,p1), o1 = MAX2(a1,p1); \
    (L0)=e0; (L1)=MIN2(o0,e1); (L2)=MAX2(o0,e1); (L3)=MIN2(o1,e2); (L4)=MAX2(o1,e2); }

__global__ __launch_bounds__(256) void median5_kernel(const float* __restrict__ img,
                                                      float* __restrict__ out)
{
    const int W = 512, H = 512;
    const int t  = blockIdx.x * 64 + threadIdx.x;   // pixel-pair index, 0..255
    const int x0 = t * 2;                           // even column
    const int ty = blockIdx.y * 4 + threadIdx.y;    // 0..63
    const int y0 = ty * 8;                          // strip top row (V=8)
    const int p  = blockIdx.z;                      // plane

    const float* __restrict__ base = img + ((size_t)p << 18);
    float* __restrict__ obase = out + ((size_t)p << 18) + x0;

    const bool okL = (x0 >= 2);        // cols x0-2, x0-1 valid
    const bool okR = (x0 + 3 < W);     // cols x0+2, x0+3 valid

    // clamped (always in-bounds) column offsets; values fixed up by masks below
    const int colL = okL ? (x0 - 2) : 0;
    const int colR = okR ? (x0 + 2) : (x0 - 2);   // x0-2 safe here: x0=510 -> 508

    // zero-fill masks for packed f16 pairs (element 0 = low 16 bits)
    const unsigned mL0 = okL ? 0xFFFFFFFFu : 0x00000000u;  // v0 = {x-2, x-1}
    const unsigned mL1 = okL ? 0xFFFFFFFFu : 0xFFFF0000u;  // v1 = {x-1, x}
    const unsigned mR0 = okR ? 0xFFFFFFFFu : 0x0000FFFFu;  // v3 = {x+1, x+2}
    const unsigned mR1 = okR ? 0xFFFFFFFFu : 0x00000000u;  // v4 = {x+2, x+3}

    h2 r[5][5];  // ring of 5 sorted rows (each entry = {px0 val, px1 val})

#define LOAD_ROW(yy, SL) do { \
    const int _y = (yy); \
    if ((unsigned)_y < (unsigned)H) { \
        const float* _rp = base + _y * W; \
        float2 l0 = *(const float2*)(_rp + colL); \
        float2 l1 = *(const float2*)(_rp + x0); \
        float2 l2 = *(const float2*)(_rp + colR); \
        h2 v0 = andmask(__builtin_amdgcn_cvt_pkrtz(l0.x, l0.y), mL0); \
        h2 v1 = andmask(__builtin_amdgcn_cvt_pkrtz(l0.y, l1.x), mL1); \
        h2 v2 = __builtin_amdgcn_cvt_pkrtz(l1.x, l1.y); \
        h2 v3 = andmask(__builtin_amdgcn_cvt_pkrtz(l1.y, l2.x), mR0); \
        h2 v4 = andmask(__builtin_amdgcn_cvt_pkrtz(l2.x, l2.y), mR1); \
        SORT4; \
        cswap(v3,v4); cswap(v2,v3); cswap(v1,v2); cswap(v0,v1); \
        r[SL][0]=v0; r[SL][1]=v1; r[SL][2]=v2; r[SL][3]=v3; r[SL][4]=v4; \
    } else { \
        h2 z = {(__fp16)0.f, (__fp16)0.f}; \
        r[SL][0]=z; r[SL][1]=z; r[SL][2]=z; r[SL][3]=z; r[SL][4]=z; \
    } \
} while (0)

    LOAD_ROW(y0 - 2, 0);
    LOAD_ROW(y0 - 1, 1);
    LOAD_ROW(y0 + 0, 2);
    LOAD_ROW(y0 + 1, 3);

#define PROC(i, RA, RB, RC, RD, RE) do { \
    LOAD_ROW(y0 + (i) + 2, RE); \
    h2 a0,a1, p0,p1,p2, mm0,mm1,mm2, q0,q1,q2, d0,d1; \
    COL_TOP2(r[RA][0], r[RB][0], r[RC][0], r[RD][0], r[RE][0], a0, a1); \
    COL_TOP3(r[RA][1], r[RB][1], r[RC][1], r[RD][1], r[RE][1], p0, p1, p2); \
    COL_MID3(r[RA][2], r[RB][2], r[RC][2], r[RD][2], r[RE][2], mm0, mm1, mm2); \
    COL_BOT3(r[RA][3], r[RB][3], r[RC][3], r[RD][3], r[RE][3], q0, q1, q2); \
    COL_BOT2(r[RA][4], r[RB][4], r[RC][4], r[RD][4], r[RE][4], d0, d1); \
    h2 L0,L1,L2,L3,L4, R0,R1,R2,R3,R4; \
    MERGE23(a0, a1, p0, p1, p2, L0, L1, L2, L3, L4); \
    MERGE23(d0, d1, q0, q1, q2, R0, R1, R2, R3, R4); \
    /* pruned odd-even merge(5,5): ranks 4..7 of L∪R */ \
    h2 u  = MAX2(L1,R1), v  = MIN2(L3,R3); \
    h2 O1 = MIN2(u,v),   O2 = MAX2(u,v); \
    h2 u2 = MAX2(L0,R0), v2 = MIN2(L4,R4); \
    h2 F1 = MIN2(u2,v2), F2 = MAX2(u2,v2); \
    h2 G0 = MIN2(L2,R2), G1 = MAX2(L2,R2); \
    h2 E2 = MAX2(G0,F1), E3 = MIN2(G1,F2); \
    h2 Sa = MIN2(O1,E2), Sb = MAX2(O1,E2); \
    h2 Sc = MIN2(O2,E3), Sd = MAX2(O2,E3); \
    /* 7th of S(10) ∪ M(3): split identity */ \
    h2 med = MIN2( MIN2(MAX2(Sa,mm2), MAX2(Sb,mm1)), \
                   MIN2(MAX2(Sc,mm0), Sd) ); \
    float2 o; \
    o.x = (float)med.x; \
    o.y = (float)med.y; \
    *reinterpret_cast<float2*>(obase + (y0 + (i)) * W) = o; \
} while (0)

    PROC(0, 0, 1, 2, 3, 4);
    PROC(1, 1, 2, 3, 4, 0);
    PROC(2, 2, 3, 4, 0, 1);
    PROC(3, 3, 4, 0, 1, 2);
    PROC(4, 4, 0, 1, 2, 3);
    PROC(5, 0, 1, 2, 3, 4);
    PROC(6, 1, 2, 3, 4, 0);
    PROC(7, 2, 3, 4, 0, 1);
}

extern "C" void kernel_launch(void* const* d_in, const int* in_sizes, int n_in,
                              void* d_out, int out_size, void* d_ws, size_t ws_size,
                              hipStream_t stream)
{
    const float* img = (const float*)d_in[0];
    float* out = (float*)d_out;

    dim3 block(64, 4, 1);
    dim3 grid(512 / 2 / 64, 512 / 8 / 4, 24);  // (4, 16, 24) = 1536 blocks
    median5_kernel<<<grid, block, 0, stream>>>(img, out);
}

// Round 10
// 86.725 us; speedup vs baseline: 1.0353x; 1.0353x over previous
//
#include <hip/hip_runtime.h>

// 5x5 median, zero pad. Packed-f16, 2 px/lane, V=8 strip.
// R9: vertical PAIR sharing — two adjacent output rows share 4 of their 5
// window rows. Per column: sort the shared 4 once (tournament where only
// top2/bot2 needed), then insert each window's private 5th element with a
// pruned insertion chain. Column work per output pair: 144 -> 88 pk-ops.
// Select: Batcher merge(2,3)x2 + pruned merge(5,5) ranks 4..7 + split identity
// (verified exact in fp32 R2, absmax==0).
// Correctness: fp16 conversion is monotone -> median(cvt(x)) == cvt(median(x));
// only error is fp16 rounding of the final median (measured absmax 7.8e-3,
// threshold 2.8e-2). Input is randn -> no NaN/inf concerns.

typedef __fp16 h2 __attribute__((ext_vector_type(2)));

#define MIN2(a, b) __builtin_elementwise_min((a), (b))
#define MAX2(a, b) __builtin_elementwise_max((a), (b))

__device__ __forceinline__ void cswap(h2& a, h2& b) {
    h2 lo = MIN2(a, b);
    h2 hi = MAX2(a, b);
    a = lo; b = hi;
}

#define SORT4 { cswap(v0,v1); cswap(v2,v3); cswap(v0,v2); cswap(v1,v3); cswap(v1,v2); }
// in-place ascending sort of 4 named values (5 CE)
#define CSORT4(a,b,c,d) { cswap(a,b); cswap(c,d); cswap(a,c); cswap(b,d); cswap(b,c); }

// odd-even merge(2,3): sorted (a0<=a1) + (p0<=p1<=p2) -> sorted L0..L4
#define MERGE23(a0,a1,p0,p1,p2,L0,L1,L2,L3,L4) { \
    h2 e0 = MIN2(a0,p0), t = MAX2(a0,p0); \
    h2 e1 = MIN2(t,p2),  e2 = MAX2(t,p2); \
    h2 o0 = MIN2(a1,p1), o1 = MAX2(a1,p1); \
    (L0)=e0; (L1)=MIN2(o0,e1); (L2)=MAX2(o0,e1); (L3)=MIN2(o1,e2); (L4)=MAX2(o1,e2); }

// 7th-of-13 band select + store (band: a=top2(c0), p=top3(c1), mm=mid3(c2),
// q=bot3(c3), d=bot2(c4)); verified exact in fp32 (R2).
#define SELECT_STORE(a0,a1,p0,p1,p2,mm0,mm1,mm2,q0,q1,q2,d0,d1, orow) { \
    h2 L0,L1,L2,L3,L4, R0,R1,R2,R3,R4; \
    MERGE23(a0, a1, p0, p1, p2, L0, L1, L2, L3, L4); \
    MERGE23(d0, d1, q0, q1, q2, R0, R1, R2, R3, R4); \
    h2 u  = MAX2(L1,R1), v  = MIN2(L3,R3); \
    h2 O1 = MIN2(u,v),   O2 = MAX2(u,v); \
    h2 u2 = MAX2(L0,R0), v2 = MIN2(L4,R4); \
    h2 F1 = MIN2(u2,v2), F2 = MAX2(u2,v2); \
    h2 G0 = MIN2(L2,R2), G1 = MAX2(L2,R2); \
    h2 E2 = MAX2(G0,F1), E3 = MIN2(G1,F2); \
    h2 Sa = MIN2(O1,E2), Sb = MAX2(O1,E2); \
    h2 Sc = MIN2(O2,E3), Sd = MAX2(O2,E3); \
    h2 med = MIN2( MIN2(MAX2(Sa,mm2), MAX2(Sb,mm1)), \
                   MIN2(MAX2(Sc,mm0), Sd) ); \
    float2 o; \
    o.x = (float)med.x; \
    o.y = (float)med.y; \
    *reinterpret_cast<float2*>(obase + (orow) * W) = o; \
}

__global__ __launch_bounds__(256) void median5_kernel(const float* __restrict__ img,
                                                      float* __restrict__ out)
{
    const int W = 512, H = 512;
    const int t  = blockIdx.x * 64 + threadIdx.x;   // pixel-pair index, 0..255
    const int x0 = t * 2;                           // even column
    const int ty = blockIdx.y * 4 + threadIdx.y;    // 0..63
    const int y0 = ty * 8;                          // strip top row (V=8)
    const int p  = blockIdx.z;                      // plane

    const float* __restrict__ base = img + ((size_t)p << 18);
    float* __restrict__ obase = out + ((size_t)p << 18) + x0;

    const bool okL = (x0 >= 2);        // l0 covers cols x0-2, x0-1
    const bool okR = (x0 + 3 < W);     // l2 covers cols x0+2, x0+3

    h2 r[6][5];  // ring of 6 sorted rows (each entry = {px0 val, px1 val})

#define LOAD_ROW(yy, SL) do { \
    const int _y = (yy); \
    if ((unsigned)_y < (unsigned)H) { \
        const float* _rp = base + _y * W + x0; \
        float2 l0 = okL ? *(const float2*)(_rp - 2) : make_float2(0.f, 0.f); \
        float2 l1 = *(const float2*)(_rp); \
        float2 l2 = okR ? *(const float2*)(_rp + 2) : make_float2(0.f, 0.f); \
        h2 v0 = __builtin_amdgcn_cvt_pkrtz(l0.x, l0.y); \
        h2 v1 = __builtin_amdgcn_cvt_pkrtz(l0.y, l1.x); \
        h2 v2 = __builtin_amdgcn_cvt_pkrtz(l1.x, l1.y); \
        h2 v3 = __builtin_amdgcn_cvt_pkrtz(l1.y, l2.x); \
        h2 v4 = __builtin_amdgcn_cvt_pkrtz(l2.x, l2.y); \
        SORT4; \
        cswap(v3,v4); cswap(v2,v3); cswap(v1,v2); cswap(v0,v1); \
        r[SL][0]=v0; r[SL][1]=v1; r[SL][2]=v2; r[SL][3]=v3; r[SL][4]=v4; \
    } else { \
        h2 z = {(__fp16)0.f, (__fp16)0.f}; \
        r[SL][0]=z; r[SL][1]=z; r[SL][2]=z; r[SL][3]=z; r[SL][4]=z; \
    } \
} while (0)

    // PAIR(i, EA, S1,S2,S3,S4, EB): outputs rows y0+i (shared4 + slot EA) and
    // y0+i+1 (shared4 + slot EB). Shared slots in any order (sorted anyway).
#define PAIR(i, EA, S1, S2, S3, S4, EB) do { \
    h2 Aa0,Aa1, Ap0,Ap1,Ap2, Am0,Am1,Am2, Aq0,Aq1,Aq2, Ad0,Ad1; \
    h2 Ba0,Ba1, Bp0,Bp1,Bp2, Bm0,Bm1,Bm2, Bq0,Bq1,Bq2, Bd0,Bd1; \
    /* col 0: top2 of shared4 (tournament), insert e -> top2 of 5 */ \
    { h2 m01=MAX2(r[S1][0],r[S2][0]), n01=MIN2(r[S1][0],r[S2][0]); \
      h2 m23=MAX2(r[S3][0],r[S4][0]), n23=MIN2(r[S3][0],r[S4][0]); \
      h2 s3=MAX2(m01,m23); \
      h2 s2=MAX2(MIN2(m01,m23), MAX2(n01,n23)); \
      { h2 e=r[EA][0]; Aa1=MAX2(s3,e); Aa0=MAX2(s2,MIN2(s3,e)); } \
      { h2 e=r[EB][0]; Ba1=MAX2(s3,e); Ba0=MAX2(s2,MIN2(s3,e)); } } \
    /* col 1: sort4, insert -> top3 of 5 (ranks 2,3,4) */ \
    { h2 s0=r[S1][1], s1=r[S2][1], s2=r[S3][1], s3=r[S4][1]; \
      CSORT4(s0,s1,s2,s3); \
      { h2 e=r[EA][1], m=MIN2(s3,e); Ap2=MAX2(s3,e); Ap1=MAX2(s2,m); \
        m=MIN2(s2,m); Ap0=MAX2(s1,m); } \
      { h2 e=r[EB][1], m=MIN2(s3,e); Bp2=MAX2(s3,e); Bp1=MAX2(s2,m); \
        m=MIN2(s2,m); Bp0=MAX2(s1,m); } } \
    /* col 2: sort4, insert -> mid3 of 5 (ranks 1,2,3) */ \
    { h2 s0=r[S1][2], s1=r[S2][2], s2=r[S3][2], s3=r[S4][2]; \
      CSORT4(s0,s1,s2,s3); \
      { h2 e=r[EA][2], m=MIN2(s3,e); Am2=MAX2(s2,m); m=MIN2(s2,m); \
        Am1=MAX2(s1,m); m=MIN2(s1,m); Am0=MAX2(s0,m); } \
      { h2 e=r[EB][2], m=MIN2(s3,e); Bm2=MAX2(s2,m); m=MIN2(s2,m); \
        Bm1=MAX2(s1,m); m=MIN2(s1,m); Bm0=MAX2(s0,m); } } \
    /* col 3: sort4, insert -> bot3 of 5 (ranks 0,1,2) */ \
    { h2 s0=r[S1][3], s1=r[S2][3], s2=r[S3][3], s3=r[S4][3]; \
      CSORT4(s0,s1,s2,s3); \
      { h2 e=r[EA][3], m=MAX2(s0,e); Aq0=MIN2(s0,e); Aq1=MIN2(s1,m); \
        m=MAX2(s1,m); Aq2=MIN2(s2,m); } \
      { h2 e=r[EB][3], m=MAX2(s0,e); Bq0=MIN2(s0,e); Bq1=MIN2(s1,m); \
        m=MAX2(s1,m); Bq2=MIN2(s2,m); } } \
    /* col 4: bot2 of shared4 (tournament), insert -> bot2 of 5 */ \
    { h2 m01=MAX2(r[S1][4],r[S2][4]), n01=MIN2(r[S1][4],r[S2][4]); \
      h2 m23=MAX2(r[S3][4],r[S4][4]), n23=MIN2(r[S3][4],r[S4][4]); \
      h2 s0=MIN2(n01,n23); \
      h2 s1=MIN2(MAX2(n01,n23), MIN2(m01,m23)); \
      { h2 e=r[EA][4]; Ad0=MIN2(s0,e); Ad1=MIN2(s1,MAX2(s0,e)); } \
      { h2 e=r[EB][4]; Bd0=MIN2(s0,e); Bd1=MIN2(s1,MAX2(s0,e)); } } \
    SELECT_STORE(Aa0,Aa1,Ap0,Ap1,Ap2,Am0,Am1,Am2,Aq0,Aq1,Aq2,Ad0,Ad1, y0+(i)); \
    SELECT_STORE(Ba0,Ba1,Bp0,Bp1,Bp2,Bm0,Bm1,Bm2,Bq0,Bq1,Bq2,Bd0,Bd1, y0+(i)+1); \
} while (0)

    // preload rows y0-2 .. y0+3 into slots 0..5
    LOAD_ROW(y0 - 2, 0);
    LOAD_ROW(y0 - 1, 1);
    LOAD_ROW(y0 + 0, 2);
    LOAD_ROW(y0 + 1, 3);
    LOAD_ROW(y0 + 2, 4);
    LOAD_ROW(y0 + 3, 5);

    PAIR(0, 0, 1, 2, 3, 4, 5);      // rows y0-2..y0+3

    LOAD_ROW(y0 + 4, 0);
    LOAD_ROW(y0 + 5, 1);
    PAIR(2, 2, 3, 4, 5, 0, 1);      // rows y0..y0+5

    LOAD_ROW(y0 + 6, 2);
    LOAD_ROW(y0 + 7, 3);
    PAIR(4, 4, 5, 0, 1, 2, 3);      // rows y0+2..y0+7

    LOAD_ROW(y0 + 8, 4);
    LOAD_ROW(y0 + 9, 5);
    PAIR(6, 0, 1, 2, 3, 4, 5);      // rows y0+4..y0+9
}

extern "C" void kernel_launch(void* const* d_in, const int* in_sizes, int n_in,
                              void* d_out, int out_size, void* d_ws, size_t ws_size,
                              hipStream_t stream)
{
    const float* img = (const float*)d_in[0];
    float* out = (float*)d_out;

    dim3 block(64, 4, 1);
    dim3 grid(512 / 2 / 64, 512 / 8 / 4, 24);  // (4, 16, 24) = 1536 blocks
    median5_kernel<<<grid, block, 0, stream>>>(img, out);
}